// Round 11
// baseline (261.959 us; speedup 1.0000x reference)
//
#include <hip/hip_runtime.h>

typedef __bf16 bf16_t;
typedef __bf16 bf16x8 __attribute__((ext_vector_type(8)));
typedef float f32x4 __attribute__((ext_vector_type(4)));

#define MFMA16(A, B, C) __builtin_amdgcn_mfma_f32_16x16x32_bf16(A, B, C, 0, 0, 0)

static constexpr int N_CODE = 8192;

// ---- workspace layout (bytes) ----
static constexpr size_t OFF_B1   = 0;                   // W_ih^T packed [48][8][64][8]  393216
static constexpr size_t OFF_B2   = OFF_B1 + 393216;     // W_hh^T packed                 393216
static constexpr size_t OFF_B3   = OFF_B2 + 393216;     // [Wq|Wk] packed                131072
static constexpr size_t OFF_BV   = OFF_B3 + 131072;     // Wv packed                     131072
static constexpr size_t OFF_BIAS = OFF_BV + 131072;     // 2048 f32
static constexpr size_t OFF_U1   = OFF_BIAS + 8192;     // 256 u32
static constexpr size_t OFF_U23  = OFF_U1 + 1024;       // 256 u32
static constexpr size_t OFF_CNT  = OFF_U23 + 1024;      // counts[0]=nS, counts[1]=nM1
static constexpr size_t OFF_IDXS = OFF_CNT + 256;       // 8192 i32
static constexpr size_t OFF_IDXM = OFF_IDXS + 32768;    // 8192 i32
static constexpr size_t OFF_A    = OFF_IDXM + 32768;    // region A: 12582912
static constexpr size_t OFF_B    = OFF_A + 12582912;    // region B: 12582912
static constexpr size_t OFF_EXT  = OFF_B + 12582912;    // extended pO (ksplit<=8; larger tiers hit
                                                        // first-touch page cost, 31ms, round 7)
// region A: phase1 gxc[<=8192][768] bf16; phase2 Kp@+0 (2MB), Vp@+2M (4MB), pml@+6291456 (512KB m,l)
// region B: phase1 ghc[<=8192][768] bf16; phase2 G3c(Q|K)@+0 (4MB), Vt@+8388608 (4MB, dead after pack),
//           fallback pO@+4194304 (8MB, ksplit=2 only)
// NOTE (round 9): NO device-scope fences / cross-block done-counters (+60us XCD L2 writeback).

__device__ __forceinline__ unsigned umap_f(float f) {
    unsigned u = __float_as_uint(f);
    return (u & 0x80000000u) ? ~u : (u | 0x80000000u);   // monotone: larger float -> larger uint
}
__device__ __forceinline__ float unmap_f(unsigned u) {
    unsigned b = (u & 0x80000000u) ? (u & 0x7fffffffu) : ~u;
    return __uint_as_float(b);
}

// ---- fused: block 0 = compaction scan (shfl-based, 2 barriers); blocks 1..128 = weight pack ----
__global__ __launch_bounds__(1024)
void tl_prep_scan(const float* __restrict__ W_ih, const float* __restrict__ W_hh,
                  const float* __restrict__ Wq, const float* __restrict__ Wk,
                  const float* __restrict__ Wv,
                  const float* __restrict__ b_ih, const float* __restrict__ b_hh,
                  const float* __restrict__ bq, const float* __restrict__ bk,
                  const float* __restrict__ bv,
                  const int* __restrict__ divided,
                  bf16_t* __restrict__ B1p, bf16_t* __restrict__ B2p,
                  bf16_t* __restrict__ B3p, bf16_t* __restrict__ BVp,
                  float* __restrict__ biases,
                  unsigned* __restrict__ u1, unsigned* __restrict__ u23,
                  int* __restrict__ idxS, int* __restrict__ idxM1, int* __restrict__ counts)
{
    int t = threadIdx.x;
    if (blockIdx.x == 0) {
        __shared__ int w1[16], w23[16];
        int lane = t & 63, wv = t >> 6;
        int d[8]; int c1 = 0, c23 = 0;
#pragma unroll
        for (int i = 0; i < 8; ++i) {
            d[i] = divided[t*8 + i];
            c1  += (d[i] == 0);
            c23 += (d[i] != 0);
        }
        int s1v = c1, s23v = c23;
#pragma unroll
        for (int off = 1; off < 64; off <<= 1) {
            int a1  = __shfl_up(s1v,  off, 64);
            int a23 = __shfl_up(s23v, off, 64);
            if (lane >= off) { s1v += a1; s23v += a23; }
        }
        if (lane == 63) { w1[wv] = s1v; w23[wv] = s23v; }
        __syncthreads();
        if (wv == 0 && lane < 16) {
            int v1 = w1[lane], v23 = w23[lane];
#pragma unroll
            for (int off = 1; off < 16; off <<= 1) {
                int a1  = __shfl_up(v1,  off, 16);
                int a23 = __shfl_up(v23, off, 16);
                if (lane >= off) { v1 += a1; v23 += a23; }
            }
            w1[lane] = v1; w23[lane] = v23;
        }
        __syncthreads();
        int base1  = (wv > 0) ? w1[wv-1]  : 0;
        int base23 = (wv > 0) ? w23[wv-1] : 0;
        int o1  = base1  + s1v  - c1;
        int o23 = base23 + s23v - c23;
#pragma unroll
        for (int i = 0; i < 8; ++i) {
            if (d[i] == 0) idxM1[o1++] = t*8 + i;
            else           idxS[o23++] = t*8 + i;
        }
        if (t == 1023) { counts[0] = w23[15]; counts[1] = w1[15]; }
        return;
    }
    int idx = (blockIdx.x - 1) * 1024 + t;
    const int T1 = 196608, T2 = 196608, T3 = 65536, T4 = 65536;
    for (int i = idx; i < T1 + T2 + T3 + T4; i += 128 * 1024) {
        int which, l;
        if (i < T1)                { which = 0; l = i; }
        else if (i < T1 + T2)      { which = 1; l = i - T1; }
        else if (i < T1 + T2 + T3) { which = 2; l = i - T1 - T2; }
        else                       { which = 3; l = i - T1 - T2 - T3; }
        int j = l & 7, lane = (l >> 3) & 63, kk = (l >> 9) & 7, n16 = l >> 12;
        int k = kk*32 + (lane >> 4)*8 + j;      // K index 0..255
        int n = n16*16 + (lane & 15);           // output column
        if (which == 0)      B1p[l] = (bf16_t)W_ih[n*256 + k];
        else if (which == 1) B2p[l] = (bf16_t)W_hh[n*256 + k];
        else if (which == 2) B3p[l] = (bf16_t)((n < 128) ? Wq[k*128 + n] : Wk[k*128 + (n - 128)]);
        else                 BVp[l] = (bf16_t)Wv[k*256 + n];
    }
    if (idx < 768)       biases[idx] = b_ih[idx];
    else if (idx < 1536) biases[idx] = b_hh[idx - 768];
    else if (idx < 1792) { int q = idx - 1536; biases[idx] = (q < 128) ? bq[q] : bk[q - 128]; }
    else if (idx < 2048) biases[idx] = bv[idx - 1792];
    if (idx < 256) { u1[idx] = 0x007FFFFFu; u23[idx] = 0x007FFFFFu; }  // umap(-inf)
}

__device__ __forceinline__ bf16x8 load_cvt8(const float* p) {
    f32x4 a = *(const f32x4*)p;
    f32x4 b = *(const f32x4*)(p + 4);
    bf16x8 r;
#pragma unroll
    for (int j = 0; j < 4; ++j) { r[j] = (bf16_t)a[j]; r[j+4] = (bf16_t)b[j]; }
    return r;
}

// ---- paired gathered GEMM: two independent GEMMs split on blockIdx.y ----
__global__ __launch_bounds__(256, 4)
void tl_gemm_pair(const float* __restrict__ A0a, const float* __restrict__ A1a,
                  const int* __restrict__ divided, int modea,
                  const bf16_t* __restrict__ Bpa, const float* __restrict__ biasa,
                  bf16_t* __restrict__ Ca, int NOUTa, int ySplit,
                  const float* __restrict__ A0b,
                  const bf16_t* __restrict__ Bpb, const float* __restrict__ biasb,
                  bf16_t* __restrict__ Cb, int NOUTb,
                  const int* __restrict__ gidx, const int* __restrict__ counts, int csel)
{
    int cnt = counts[csel];
    int m0  = blockIdx.x * 64;
    if (m0 >= cnt) return;
    int y = blockIdx.y;
    const float* A0; const float* A1 = nullptr; int mode;
    const bf16_t* Bp; const float* bias; bf16_t* C; int NOUT; int y0;
    if (y < ySplit) { A0 = A0a; A1 = A1a; mode = modea; Bp = Bpa; bias = biasa; C = Ca; NOUT = NOUTa; y0 = y; }
    else            { A0 = A0b; mode = 0;               Bp = Bpb; bias = biasb; C = Cb; NOUT = NOUTb; y0 = y - ySplit; }

    int lane = threadIdx.x & 63;
    int w    = threadIdx.x >> 6;
    int n0   = y0 * 64 + w * 16;
    int rlo = lane & 15, khi = lane >> 4;

    const float* arow[4];
#pragma unroll
    for (int m = 0; m < 4; ++m) {
        int row = m0 + m*16 + rlo;
        int src = gidx[(row < cnt) ? row : 0];
        const float* base = A0;
        if (mode == 2) base = (divided[src] == 1) ? A0 : A1;
        arow[m] = base + (size_t)src * 256;
    }
    f32x4 acc[4] = {};
    const bf16_t* bptr = Bp + (size_t)(n0 >> 4) * 4096 + lane * 8;
#pragma unroll
    for (int kk = 0; kk < 8; ++kk) {
        bf16x8 bfrag = *(const bf16x8*)(bptr + kk * 512);
#pragma unroll
        for (int m = 0; m < 4; ++m) {
            bf16x8 afrag = load_cvt8(arow[m] + kk*32 + khi*8);
            acc[m] = MFMA16(afrag, bfrag, acc[m]);
        }
    }
    int col = n0 + rlo;
    float b = bias[col];
#pragma unroll
    for (int m = 0; m < 4; ++m)
#pragma unroll
        for (int r = 0; r < 4; ++r) {
            int row = m0 + m*16 + khi*4 + r;   // compact row index
            C[(size_t)row * NOUT + col] = (bf16_t)(acc[m][r] + b);
        }
}

// ---- GRU elementwise on compact m1 rows (8 rows/block); fp32 h_new + column-max atomics ----
__global__ void tl_gru(const bf16_t* __restrict__ gx, const bf16_t* __restrict__ gh,
                       const float* __restrict__ hidden,
                       const int* __restrict__ idxM1, const int* __restrict__ counts,
                       float* __restrict__ h_new, unsigned* __restrict__ u1)
{
    int nM1 = counts[1];
    int i0 = blockIdx.x * 8;
    if (i0 >= nM1) return;
    int j = threadIdx.x;          // 0..255
    int iend = (i0 + 8 < nM1) ? i0 + 8 : nM1;
    float cmax = -1e30f;
    for (int i = i0; i < iend; ++i) {
        int row = idxM1[i];
        float xr = (float)gx[(size_t)i*768 + j];
        float xz = (float)gx[(size_t)i*768 + 256 + j];
        float xn = (float)gx[(size_t)i*768 + 512 + j];
        float hr = (float)gh[(size_t)i*768 + j];
        float hz = (float)gh[(size_t)i*768 + 256 + j];
        float hn = (float)gh[(size_t)i*768 + 512 + j];
        float h  = hidden[(size_t)row*256 + j];
        float r = 1.f/(1.f + __expf(-(xr + hr)));
        float z = 1.f/(1.f + __expf(-(xz + hz)));
        float n = tanhf(xn + r*hn);
        float hg = (1.f - z)*n + z*h;
        h_new[(size_t)row*256 + j] = hg;
        cmax = fmaxf(cmax, hg);
    }
    atomicMax(&u1[j], umap_f(cmax));
}

// ---- pack compact K (G3c cols 128..255) and V (Vt) into MFMA b-frag layouts, zero-pad to 64 ----
__global__ void tl_pack(const bf16_t* __restrict__ G3c, const bf16_t* __restrict__ Vt,
                        const int* __restrict__ counts,
                        bf16_t* __restrict__ Kp, bf16_t* __restrict__ Vp)
{
    int nS = counts[0];
    int nT = (nS + 63) >> 6;
    int r = blockIdx.x;
    if (r >= nT * 64) return;
    int t = threadIdx.x;          // 0..63
    bool valid = r < nS;
    if (t < 16) {                 // K b-frags: [kt][ks4][nf4][lane][8]
        bf16x8 v = {};
        if (valid) v = *(const bf16x8*)(G3c + (size_t)r*256 + 128 + t*8);
        int kt = r >> 6, keyin = r & 63;
        int ks = t >> 2, lhi = t & 3, nf = keyin >> 4;
        int lane = (lhi << 4) | (keyin & 15);
        *(bf16x8*)(Kp + ((((size_t)kt*4 + ks)*4 + nf)*64 + lane)*8) = v;
    } else if (t < 48) {          // V b-frags: [kt][ks2][nf16][lane][8]
        int j8 = t - 16;          // 0..31
        int d0 = j8 * 8;
        bf16x8 v = {};
        if (valid) v = *(const bf16x8*)(Vt + (size_t)r*256 + d0);
        int kt = r >> 6, ks2 = (r >> 5) & 1, jj = r & 7, lhi = (r >> 3) & 3;
#pragma unroll
        for (int q = 0; q < 8; ++q) {
            int d = d0 + q;
            int nf = d >> 4;
            int lane = (lhi << 4) | (d & 15);
            Vp[((((size_t)kt*2 + ks2)*16 + nf)*64 + lane)*8 + jj] = v[q];
        }
    }
}

// ---- flash attention: R5 per-wave math + block-shared LDS K/V staging (4x traffic cut) ----
// grid = (ksplit, 128): linear block id % 8 == split id -> same-split blocks share an XCD L2
// (heuristic; perf-only). Per tile: reg-stage 48KB K+V (T14: next tile's loads issued before
// compute so L2 latency hides under MFMA), all 4 waves read LDS instead of 4x-redundant L2.
__global__ __launch_bounds__(256, 2)
void tl_attn(const bf16_t* __restrict__ G3c, const bf16_t* __restrict__ Kp,
             const bf16_t* __restrict__ Vp, const int* __restrict__ counts,
             int ksplit, float* __restrict__ pml, bf16_t* __restrict__ pO)
{
    int nS = counts[0];
    int nT = (nS + 63) >> 6;
    int qt = blockIdx.y;
    if (qt >= nT) return;
    int c = blockIdx.x;
    int kt0 = (nT * c) / ksplit, kt1 = (nT * (c + 1)) / ksplit;

    int tid  = threadIdx.x;
    int lane = tid & 63;
    int w    = tid >> 6;
    int rlo = lane & 15, khi = lane >> 4;
    int qbase = qt * 64 + w * 16;

    __shared__ __align__(16) bf16_t KV[24576];          // 48KB: K [0,8192) | V [8192,24576) bf16
    __shared__ __align__(16) bf16_t P_lds[4][16][72];   // per-wave private strip
    uint4* s4 = (uint4*)KV;

    bf16x8 aQ[4];
    const bf16_t* qrow = G3c + (size_t)(qbase + rlo) * 256 + khi * 8;
#pragma unroll
    for (int ks = 0; ks < 4; ++ks) aQ[ks] = *(const bf16x8*)(qrow + ks * 32);

    float m_run[4], l_run[4];
#pragma unroll
    for (int r = 0; r < 4; ++r) { m_run[r] = -1e30f; l_run[r] = 0.f; }
    f32x4 O[16];
#pragma unroll
    for (int i = 0; i < 16; ++i) O[i] = (f32x4){0.f, 0.f, 0.f, 0.f};

    const float scale = 0.088388347648318447f;   // 1/sqrt(128)

    uint4 tk[4], tv[8];
    if (kt0 < kt1) {
        const uint4* gK4 = (const uint4*)(Kp + (size_t)kt0 * 8192);
        const uint4* gV4 = (const uint4*)(Vp + (size_t)kt0 * 16384);
#pragma unroll
        for (int i = 0; i < 4; ++i) tk[i] = gK4[i*256 + tid];
#pragma unroll
        for (int i = 0; i < 8; ++i) tv[i] = gV4[i*256 + tid];
    }

    for (int kt = kt0; kt < kt1; ++kt) {
        // write staged regs (tile kt) to LDS
#pragma unroll
        for (int i = 0; i < 4; ++i) s4[i*256 + tid] = tk[i];
#pragma unroll
        for (int i = 0; i < 8; ++i) s4[1024 + i*256 + tid] = tv[i];
        __syncthreads();
        // early-issue next tile's global loads (latency hides under compute below)
        if (kt + 1 < kt1) {
            const uint4* gK4 = (const uint4*)(Kp + (size_t)(kt+1) * 8192);
            const uint4* gV4 = (const uint4*)(Vp + (size_t)(kt+1) * 16384);
#pragma unroll
            for (int i = 0; i < 4; ++i) tk[i] = gK4[i*256 + tid];
#pragma unroll
            for (int i = 0; i < 8; ++i) tv[i] = gV4[i*256 + tid];
        }
        // ---- compute tile kt from LDS (byte-identical math to round-5 form) ----
        f32x4 s[4] = {};
#pragma unroll
        for (int ks = 0; ks < 4; ++ks) {
            const bf16_t* kp = KV + ks*2048 + lane*8;
#pragma unroll
            for (int nf = 0; nf < 4; ++nf) {
                bf16x8 bK = *(const bf16x8*)(kp + nf * 512);
                s[nf] = MFMA16(aQ[ks], bK, s[nf]);
            }
        }
        int kbase = kt * 64;
#pragma unroll
        for (int nf = 0; nf < 4; ++nf) {
            bool valid = (kbase + nf*16 + rlo) < nS;
#pragma unroll
            for (int r = 0; r < 4; ++r) {
                float v = s[nf][r] * scale;
                s[nf][r] = valid ? v : -1e30f;
            }
        }
        float pm[4];
#pragma unroll
        for (int r = 0; r < 4; ++r)
            pm[r] = fmaxf(fmaxf(s[0][r], s[1][r]), fmaxf(s[2][r], s[3][r]));
#pragma unroll
        for (int off = 1; off < 16; off <<= 1)
#pragma unroll
            for (int r = 0; r < 4; ++r) pm[r] = fmaxf(pm[r], __shfl_xor(pm[r], off, 64));

        float mn[4], sc[4], rs[4];
#pragma unroll
        for (int r = 0; r < 4; ++r) {
            mn[r] = fmaxf(m_run[r], pm[r]);
            sc[r] = __expf(m_run[r] - mn[r]);
            m_run[r] = mn[r];
            rs[r] = 0.f;
        }
#pragma unroll
        for (int nf = 0; nf < 4; ++nf)
#pragma unroll
            for (int r = 0; r < 4; ++r) {
                float p = __expf(s[nf][r] - mn[r]);
                s[nf][r] = p;
                rs[r] += p;
            }
#pragma unroll
        for (int off = 1; off < 16; off <<= 1)
#pragma unroll
            for (int r = 0; r < 4; ++r) rs[r] += __shfl_xor(rs[r], off, 64);
#pragma unroll
        for (int r = 0; r < 4; ++r) l_run[r] = l_run[r]*sc[r] + rs[r];
#pragma unroll
        for (int nf = 0; nf < 16; ++nf)
#pragma unroll
            for (int r = 0; r < 4; ++r) O[nf][r] *= sc[r];
        // P -> per-wave LDS strip, read back in a-frag layout (in-wave dep, no barrier needed)
#pragma unroll
        for (int nf = 0; nf < 4; ++nf)
#pragma unroll
            for (int r = 0; r < 4; ++r)
                P_lds[w][khi*4 + r][nf*16 + rlo] = (bf16_t)s[nf][r];
#pragma unroll
        for (int ks2 = 0; ks2 < 2; ++ks2) {
            bf16x8 pa = *(const bf16x8*)&P_lds[w][rlo][ks2*32 + khi*8];
            const bf16_t* vp = KV + 8192 + ks2*8192 + lane*8;
#pragma unroll
            for (int nf = 0; nf < 16; ++nf) {
                bf16x8 bV = *(const bf16x8*)(vp + nf * 512);
                O[nf] = MFMA16(pa, bV, O[nf]);
            }
        }
        __syncthreads();   // all waves done with KV before next overwrite
    }
    if (rlo == 0) {
#pragma unroll
        for (int r = 0; r < 4; ++r) {
            int qc = qbase + khi*4 + r;
            pml[((size_t)c*N_CODE + qc)*2 + 0] = m_run[r];
            pml[((size_t)c*N_CODE + qc)*2 + 1] = l_run[r];
        }
    }
#pragma unroll
    for (int nf = 0; nf < 16; ++nf) {
        int d = nf*16 + rlo;
#pragma unroll
        for (int r = 0; r < 4; ++r) {
            int qc = qbase + khi*4 + r;
            pO[((size_t)c*N_CODE + qc)*256 + d] = (bf16_t)O[nf][r];
        }
    }
}

// ---- merge key-split partials, VECTORIZED: thread (qi,j8) owns 8 cols of one q-row ----
template<int KS>
__global__ __launch_bounds__(256)
void tl_merge_t(const bf16_t* __restrict__ pO, const float* __restrict__ pml,
                const int* __restrict__ idxS, const int* __restrict__ counts,
                float* __restrict__ h_new, unsigned* __restrict__ u23)
{
    int nS = counts[0];
    int i0 = blockIdx.x * 8;
    if (i0 >= nS) return;
    int tid = threadIdx.x;
    int qi = tid >> 5;            // 0..7 (q-row within block)
    int j8 = tid & 31;            // column octet 0..31
    int q  = i0 + qi;

    __shared__ unsigned smax[256];
    smax[tid] = 0x007FFFFFu;      // umap(-inf)
    __syncthreads();

    if (q < nS) {
        float m = -1e30f;
#pragma unroll
        for (int cc = 0; cc < KS; ++cc)
            m = fmaxf(m, pml[((size_t)cc*N_CODE + q)*2 + 0]);
        float e[KS]; float l = 0.f;
#pragma unroll
        for (int cc = 0; cc < KS; ++cc) {
            e[cc] = __expf(pml[((size_t)cc*N_CODE + q)*2 + 0] - m);
            l += pml[((size_t)cc*N_CODE + q)*2 + 1] * e[cc];
        }
        float acc[8] = {};
#pragma unroll
        for (int cc = 0; cc < KS; ++cc) {
            bf16x8 v = *(const bf16x8*)(pO + ((size_t)cc*N_CODE + q)*256 + j8*8);
#pragma unroll
            for (int k = 0; k < 8; ++k) acc[k] += (float)v[k] * e[cc];
        }
        float linv = 1.f / fmaxf(l, 1e-30f);
        f32x4 o0, o1;
#pragma unroll
        for (int k = 0; k < 8; ++k) {
            float val = tanhf(acc[k] * linv);
            if (k < 4) o0[k] = val; else o1[k-4] = val;
            atomicMax(&smax[j8*8 + k], umap_f(val));   // LDS atomic (block-local)
        }
        float* dst = h_new + (size_t)idxS[q]*256 + j8*8;
        *(f32x4*)dst = o0;
        *(f32x4*)(dst + 4) = o1;
    }
    __syncthreads();
    atomicMax(&u23[tid], smax[tid]);   // one global atomic per column per block
}

__global__ void tl_final(const unsigned* __restrict__ u1, const unsigned* __restrict__ u23,
                         float* __restrict__ out)
{
    int d = threadIdx.x;
    out[d] = fmaxf(unmap_f(u1[d]), unmap_f(u23[d]));
}

extern "C" void kernel_launch(void* const* d_in, const int* in_sizes, int n_in,
                              void* d_out, int out_size, void* d_ws, size_t ws_size,
                              hipStream_t stream) {
    const float* m_emb  = (const float*)d_in[0];
    const float* ddi    = (const float*)d_in[1];
    const float* unrel  = (const float*)d_in[2];
    const float* hidden = (const float*)d_in[3];
    const float* W_ih   = (const float*)d_in[4];
    const float* W_hh   = (const float*)d_in[5];
    const float* b_ih   = (const float*)d_in[6];
    const float* b_hh   = (const float*)d_in[7];
    const float* Wq     = (const float*)d_in[8];
    const float* bq     = (const float*)d_in[9];
    const float* Wk     = (const float*)d_in[10];
    const float* bk     = (const float*)d_in[11];
    const float* Wv     = (const float*)d_in[12];
    const float* bv     = (const float*)d_in[13];
    const int*   divided= (const int*)d_in[14];

    char* ws = (char*)d_ws;
    bf16_t* B1p   = (bf16_t*)(ws + OFF_B1);
    bf16_t* B2p   = (bf16_t*)(ws + OFF_B2);
    bf16_t* B3p   = (bf16_t*)(ws + OFF_B3);
    bf16_t* BVp   = (bf16_t*)(ws + OFF_BV);
    float*  biases= (float*)(ws + OFF_BIAS);
    unsigned* u1  = (unsigned*)(ws + OFF_U1);
    unsigned* u23 = (unsigned*)(ws + OFF_U23);
    int*    counts= (int*)(ws + OFF_CNT);
    int*    idxS  = (int*)(ws + OFF_IDXS);
    int*    idxM1 = (int*)(ws + OFF_IDXM);
    // region A
    bf16_t* gxc   = (bf16_t*)(ws + OFF_A);
    bf16_t* Kp    = (bf16_t*)(ws + OFF_A);
    bf16_t* Vp    = (bf16_t*)(ws + OFF_A + 2097152);
    float*  pml   = (float*) (ws + OFF_A + 6291456);   // (m,l) pairs: ksplit*8192*8B <= 512KB
    // region B
    bf16_t* ghc   = (bf16_t*)(ws + OFF_B);
    bf16_t* G3c   = (bf16_t*)(ws + OFF_B);
    bf16_t* Vt    = (bf16_t*)(ws + OFF_B + 8388608);

    // pick key-split factor from available workspace (capped at 8 — round-7 page-cost trap)
    int ksplit;
    bf16_t* pO;
    if (ws_size >= OFF_EXT + (size_t)8 * 4194304)      { ksplit = 8; pO = (bf16_t*)(ws + OFF_EXT); }
    else if (ws_size >= OFF_EXT + (size_t)4 * 4194304) { ksplit = 4; pO = (bf16_t*)(ws + OFF_EXT); }
    else                                               { ksplit = 2; pO = (bf16_t*)(ws + OFF_B + 4194304); }

    float* out   = (float*)d_out;
    float* h_new = out + 256;

    tl_prep_scan<<<dim3(129), dim3(1024), 0, stream>>>(W_ih, W_hh, Wq, Wk, Wv, b_ih, b_hh, bq, bk, bv,
                                                       divided, B1p, B2p, B3p, BVp, biases, u1, u23,
                                                       idxS, idxM1, counts);
    // fused: gxc = m_emb@W_ih^T (y<12) | ghc = hidden@W_hh^T (y>=12), both gathered by idxM1
    tl_gemm_pair<<<dim3(128, 24), dim3(256), 0, stream>>>(m_emb, nullptr, nullptr, 0,
                                                          B1p, biases + 0,   gxc, 768, 12,
                                                          hidden, B2p, biases + 768, ghc, 768,
                                                          idxM1, counts, 1);
    tl_gru<<<dim3(1024), dim3(256), 0, stream>>>(gxc, ghc, hidden, idxM1, counts, h_new, u1);
    // fused: G3c = select(ddi,unrel)@[Wq|Wk] (y<4) | Vt = m_emb@Wv (y>=4), gathered by idxS
    tl_gemm_pair<<<dim3(128, 8), dim3(256), 0, stream>>>(ddi, unrel, divided, 2,
                                                         B3p, biases + 1536, G3c, 256, 4,
                                                         m_emb, BVp, biases + 1792, Vt, 256,
                                                         idxS, counts, 0);
    tl_pack<<<dim3(8192), dim3(64), 0, stream>>>(G3c, Vt, counts, Kp, Vp);
    tl_attn<<<dim3(ksplit, 128), dim3(256), 0, stream>>>(G3c, Kp, Vp, counts, ksplit, pml, pO);
    if (ksplit == 8)      tl_merge_t<8><<<dim3(1024), dim3(256), 0, stream>>>(pO, pml, idxS, counts, h_new, u23);
    else if (ksplit == 4) tl_merge_t<4><<<dim3(1024), dim3(256), 0, stream>>>(pO, pml, idxS, counts, h_new, u23);
    else                  tl_merge_t<2><<<dim3(1024), dim3(256), 0, stream>>>(pO, pml, idxS, counts, h_new, u23);
    tl_final<<<dim3(1), dim3(256), 0, stream>>>(u1, u23, out);
}

// Round 12
// 182.529 us; speedup vs baseline: 1.4352x; 1.4352x over previous
//
#include <hip/hip_runtime.h>

typedef __bf16 bf16_t;
typedef __bf16 bf16x8 __attribute__((ext_vector_type(8)));
typedef float f32x4 __attribute__((ext_vector_type(4)));

#define MFMA16(A, B, C) __builtin_amdgcn_mfma_f32_16x16x32_bf16(A, B, C, 0, 0, 0)

static constexpr int N_CODE = 8192;

// ---- workspace layout (bytes), de-aliased: gxc/ghc/G3c/Vt simultaneously live ----
static constexpr size_t OFF_B1   = 0;                       // 393216
static constexpr size_t OFF_B2   = OFF_B1 + 393216;         // 393216
static constexpr size_t OFF_B3   = OFF_B2 + 393216;         // 131072
static constexpr size_t OFF_BV   = OFF_B3 + 131072;         // 131072
static constexpr size_t OFF_BIAS = OFF_BV + 131072;         // 8192
static constexpr size_t OFF_U1   = OFF_BIAS + 8192;         // 1024
static constexpr size_t OFF_U23  = OFF_U1 + 1024;           // 1024
static constexpr size_t OFF_CNT  = OFF_U23 + 1024;          // 256
static constexpr size_t OFF_IDXS = OFF_CNT + 256;           // 32768
static constexpr size_t OFF_IDXM = OFF_IDXS + 32768;        // 32768
static constexpr size_t OFF_GXC  = OFF_IDXM + 32768;        // 12582912
static constexpr size_t OFF_GHC  = OFF_GXC + 12582912;      // 12582912
static constexpr size_t OFF_G3C  = OFF_GHC + 12582912;      // 4194304
static constexpr size_t OFF_VT   = OFF_G3C + 4194304;       // 4194304
static constexpr size_t OFF_KP   = OFF_VT + 4194304;        // 2097152
static constexpr size_t OFF_VP   = OFF_KP + 2097152;        // 4194304
static constexpr size_t OFF_PML  = OFF_VP + 4194304;        // 524288
static constexpr size_t OFF_PO   = OFF_PML + 524288;        // ksplit*4194304 (<=33.5MB)
// total @ksplit=8 ~74.8MB; ws >= 92.9MB proven (round-7 tier-16 selection).
// NOTE (round 9): NO device-scope fences / cross-block done-counters (+60us XCD L2 writeback).
// NOTE (round 11): NO register-staged K/V tiles in attn (spills -> 120MB scratch writes).

__device__ __forceinline__ unsigned umap_f(float f) {
    unsigned u = __float_as_uint(f);
    return (u & 0x80000000u) ? ~u : (u | 0x80000000u);   // monotone: larger float -> larger uint
}
__device__ __forceinline__ float unmap_f(unsigned u) {
    unsigned b = (u & 0x80000000u) ? (u & 0x7fffffffu) : ~u;
    return __uint_as_float(b);
}

// ---- fused: block 0 = compaction scan (shfl-based); blocks 1..128 = weight pack ----
__global__ __launch_bounds__(1024)
void tl_prep_scan(const float* __restrict__ W_ih, const float* __restrict__ W_hh,
                  const float* __restrict__ Wq, const float* __restrict__ Wk,
                  const float* __restrict__ Wv,
                  const float* __restrict__ b_ih, const float* __restrict__ b_hh,
                  const float* __restrict__ bq, const float* __restrict__ bk,
                  const float* __restrict__ bv,
                  const int* __restrict__ divided,
                  bf16_t* __restrict__ B1p, bf16_t* __restrict__ B2p,
                  bf16_t* __restrict__ B3p, bf16_t* __restrict__ BVp,
                  float* __restrict__ biases,
                  unsigned* __restrict__ u1, unsigned* __restrict__ u23,
                  int* __restrict__ idxS, int* __restrict__ idxM1, int* __restrict__ counts)
{
    int t = threadIdx.x;
    if (blockIdx.x == 0) {
        __shared__ int w1[16], w23[16];
        int lane = t & 63, wv = t >> 6;
        int d[8]; int c1 = 0, c23 = 0;
#pragma unroll
        for (int i = 0; i < 8; ++i) {
            d[i] = divided[t*8 + i];
            c1  += (d[i] == 0);
            c23 += (d[i] != 0);
        }
        int s1v = c1, s23v = c23;
#pragma unroll
        for (int off = 1; off < 64; off <<= 1) {
            int a1  = __shfl_up(s1v,  off, 64);
            int a23 = __shfl_up(s23v, off, 64);
            if (lane >= off) { s1v += a1; s23v += a23; }
        }
        if (lane == 63) { w1[wv] = s1v; w23[wv] = s23v; }
        __syncthreads();
        if (wv == 0 && lane < 16) {
            int v1 = w1[lane], v23 = w23[lane];
#pragma unroll
            for (int off = 1; off < 16; off <<= 1) {
                int a1  = __shfl_up(v1,  off, 16);
                int a23 = __shfl_up(v23, off, 16);
                if (lane >= off) { v1 += a1; v23 += a23; }
            }
            w1[lane] = v1; w23[lane] = v23;
        }
        __syncthreads();
        int base1  = (wv > 0) ? w1[wv-1]  : 0;
        int base23 = (wv > 0) ? w23[wv-1] : 0;
        int o1  = base1  + s1v  - c1;
        int o23 = base23 + s23v - c23;
#pragma unroll
        for (int i = 0; i < 8; ++i) {
            if (d[i] == 0) idxM1[o1++] = t*8 + i;
            else           idxS[o23++] = t*8 + i;
        }
        if (t == 1023) { counts[0] = w23[15]; counts[1] = w1[15]; }
        return;
    }
    int idx = (blockIdx.x - 1) * 1024 + t;
    const int T1 = 196608, T2 = 196608, T3 = 65536, T4 = 65536;
    for (int i = idx; i < T1 + T2 + T3 + T4; i += 128 * 1024) {
        int which, l;
        if (i < T1)                { which = 0; l = i; }
        else if (i < T1 + T2)      { which = 1; l = i - T1; }
        else if (i < T1 + T2 + T3) { which = 2; l = i - T1 - T2; }
        else                       { which = 3; l = i - T1 - T2 - T3; }
        int j = l & 7, lane = (l >> 3) & 63, kk = (l >> 9) & 7, n16 = l >> 12;
        int k = kk*32 + (lane >> 4)*8 + j;      // K index 0..255
        int n = n16*16 + (lane & 15);           // output column
        if (which == 0)      B1p[l] = (bf16_t)W_ih[n*256 + k];
        else if (which == 1) B2p[l] = (bf16_t)W_hh[n*256 + k];
        else if (which == 2) B3p[l] = (bf16_t)((n < 128) ? Wq[k*128 + n] : Wk[k*128 + (n - 128)]);
        else                 BVp[l] = (bf16_t)Wv[k*256 + n];
    }
    if (idx < 768)       biases[idx] = b_ih[idx];
    else if (idx < 1536) biases[idx] = b_hh[idx - 768];
    else if (idx < 1792) { int q = idx - 1536; biases[idx] = (q < 128) ? bq[q] : bk[q - 128]; }
    else if (idx < 2048) biases[idx] = bv[idx - 1792];
    if (idx < 256) { u1[idx] = 0x007FFFFFu; u23[idx] = 0x007FFFFFu; }  // umap(-inf)
}

__device__ __forceinline__ bf16x8 load_cvt8(const float* p) {
    f32x4 a = *(const f32x4*)p;
    f32x4 b = *(const f32x4*)(p + 4);
    bf16x8 r;
#pragma unroll
    for (int j = 0; j < 4; ++j) { r[j] = (bf16_t)a[j]; r[j+4] = (bf16_t)b[j]; }
    return r;
}

// ---- quad gathered GEMM: 4 independent GEMMs split on blockIdx.y ----
// y<12: gxc = m_emb[idxM1]@B1p | y<24: ghc = hidden[idxM1]@B2p
// y<28: G3c = sel(ddi,unrel)[idxS]@B3p | else: Vt = m_emb[idxS]@BVp
__global__ __launch_bounds__(256, 4)
void tl_gemm_quad(const float* __restrict__ m_emb, const float* __restrict__ hidden,
                  const float* __restrict__ ddi, const float* __restrict__ unrel,
                  const int* __restrict__ divided,
                  const bf16_t* __restrict__ B1p, const bf16_t* __restrict__ B2p,
                  const bf16_t* __restrict__ B3p, const bf16_t* __restrict__ BVp,
                  const float* __restrict__ biases,
                  bf16_t* __restrict__ gxc, bf16_t* __restrict__ ghc,
                  bf16_t* __restrict__ G3c, bf16_t* __restrict__ Vt,
                  const int* __restrict__ idxM1, const int* __restrict__ idxS,
                  const int* __restrict__ counts)
{
    int y = blockIdx.y;
    const float* A0; const float* A1 = nullptr; int mode = 0;
    const bf16_t* Bp; const float* bias; bf16_t* C; int NOUT; int y0;
    const int* gidx; int cnt;
    if (y < 12)      { A0 = m_emb;  gidx = idxM1; cnt = counts[1]; Bp = B1p; bias = biases;        C = gxc; NOUT = 768; y0 = y; }
    else if (y < 24) { A0 = hidden; gidx = idxM1; cnt = counts[1]; Bp = B2p; bias = biases + 768;  C = ghc; NOUT = 768; y0 = y - 12; }
    else if (y < 28) { A0 = ddi; A1 = unrel; mode = 2;
                       gidx = idxS;  cnt = counts[0]; Bp = B3p; bias = biases + 1536; C = G3c; NOUT = 256; y0 = y - 24; }
    else             { A0 = m_emb;  gidx = idxS;  cnt = counts[0]; Bp = BVp; bias = biases + 1792; C = Vt;  NOUT = 256; y0 = y - 28; }

    int m0 = blockIdx.x * 64;
    if (m0 >= cnt) return;
    int lane = threadIdx.x & 63;
    int w    = threadIdx.x >> 6;
    int n0   = y0 * 64 + w * 16;
    int rlo = lane & 15, khi = lane >> 4;

    const float* arow[4];
#pragma unroll
    for (int m = 0; m < 4; ++m) {
        int row = m0 + m*16 + rlo;
        int src = gidx[(row < cnt) ? row : 0];
        const float* base = A0;
        if (mode == 2) base = (divided[src] == 1) ? A0 : A1;
        arow[m] = base + (size_t)src * 256;
    }
    f32x4 acc[4] = {};
    const bf16_t* bptr = Bp + (size_t)(n0 >> 4) * 4096 + lane * 8;
#pragma unroll
    for (int kk = 0; kk < 8; ++kk) {
        bf16x8 bfrag = *(const bf16x8*)(bptr + kk * 512);
#pragma unroll
        for (int m = 0; m < 4; ++m) {
            bf16x8 afrag = load_cvt8(arow[m] + kk*32 + khi*8);
            acc[m] = MFMA16(afrag, bfrag, acc[m]);
        }
    }
    int col = n0 + rlo;
    float b = bias[col];
#pragma unroll
    for (int m = 0; m < 4; ++m)
#pragma unroll
        for (int r = 0; r < 4; ++r) {
            int row = m0 + m*16 + khi*4 + r;   // compact row index
            C[(size_t)row * NOUT + col] = (bf16_t)(acc[m][r] + b);
        }
}

// ---- fused gru (blocks 0..1023) + pack (blocks 1024..3071); disjoint data ----
__global__ __launch_bounds__(256)
void tl_gru_pack(const bf16_t* __restrict__ gx, const bf16_t* __restrict__ gh,
                 const float* __restrict__ hidden,
                 const int* __restrict__ idxM1, const int* __restrict__ counts,
                 float* __restrict__ h_new, unsigned* __restrict__ u1,
                 const bf16_t* __restrict__ G3c, const bf16_t* __restrict__ Vt,
                 bf16_t* __restrict__ Kp, bf16_t* __restrict__ Vp)
{
    if (blockIdx.x < 1024) {
        // ---- GRU on compact m1 rows (8 rows/block) ----
        int nM1 = counts[1];
        int i0 = blockIdx.x * 8;
        if (i0 >= nM1) return;
        int j = threadIdx.x;
        int iend = (i0 + 8 < nM1) ? i0 + 8 : nM1;
        float cmax = -1e30f;
        for (int i = i0; i < iend; ++i) {
            int row = idxM1[i];
            float xr = (float)gx[(size_t)i*768 + j];
            float xz = (float)gx[(size_t)i*768 + 256 + j];
            float xn = (float)gx[(size_t)i*768 + 512 + j];
            float hr = (float)gh[(size_t)i*768 + j];
            float hz = (float)gh[(size_t)i*768 + 256 + j];
            float hn = (float)gh[(size_t)i*768 + 512 + j];
            float h  = hidden[(size_t)row*256 + j];
            float r = 1.f/(1.f + __expf(-(xr + hr)));
            float z = 1.f/(1.f + __expf(-(xz + hz)));
            float n = tanhf(xn + r*hn);
            float hg = (1.f - z)*n + z*h;
            h_new[(size_t)row*256 + j] = hg;
            cmax = fmaxf(cmax, hg);
        }
        atomicMax(&u1[j], umap_f(cmax));
        return;
    }
    // ---- pack: 4 rows/block, each handled by one 64-lane group (same math as before) ----
    int nS = counts[0];
    int nT = (nS + 63) >> 6;
    int r = (blockIdx.x - 1024) * 4 + (threadIdx.x >> 6);
    if (r >= nT * 64) return;
    int t = threadIdx.x & 63;
    bool valid = r < nS;
    if (t < 16) {                 // K b-frags: [kt][ks4][nf4][lane][8]
        bf16x8 v = {};
        if (valid) v = *(const bf16x8*)(G3c + (size_t)r*256 + 128 + t*8);
        int kt = r >> 6, keyin = r & 63;
        int ks = t >> 2, lhi = t & 3, nf = keyin >> 4;
        int lane = (lhi << 4) | (keyin & 15);
        *(bf16x8*)(Kp + ((((size_t)kt*4 + ks)*4 + nf)*64 + lane)*8) = v;
    } else if (t < 48) {          // V b-frags: [kt][ks2][nf16][lane][8]
        int j8 = t - 16;
        int d0 = j8 * 8;
        bf16x8 v = {};
        if (valid) v = *(const bf16x8*)(Vt + (size_t)r*256 + d0);
        int kt = r >> 6, ks2 = (r >> 5) & 1, jj = r & 7, lhi = (r >> 3) & 3;
#pragma unroll
        for (int q = 0; q < 8; ++q) {
            int d = d0 + q;
            int nf = d >> 4;
            int lane = (lhi << 4) | (d & 15);
            Vp[((((size_t)kt*2 + ks2)*16 + nf)*64 + lane)*8 + jj] = v[q];
        }
    }
}

// ---- flash attention (BYTE-STABLE round-5 body); grid (ksplit, 128) so blockid%8==c
//      puts one K/V slice per XCD L2 (locality heuristic, perf-only) ----
__global__ __launch_bounds__(256, 2)
void tl_attn(const bf16_t* __restrict__ G3c, const bf16_t* __restrict__ Kp,
             const bf16_t* __restrict__ Vp, const int* __restrict__ counts,
             int ksplit, float* __restrict__ pml, bf16_t* __restrict__ pO)
{
    int nS = counts[0];
    int nT = (nS + 63) >> 6;
    int qt = blockIdx.y;
    if (qt >= nT) return;
    int c = blockIdx.x;
    int kt0 = (nT * c) / ksplit, kt1 = (nT * (c + 1)) / ksplit;

    int lane = threadIdx.x & 63;
    int w    = threadIdx.x >> 6;
    int rlo = lane & 15, khi = lane >> 4;
    int qbase = qt * 64 + w * 16;

    __shared__ __align__(16) bf16_t P_lds[4][16][72];   // per-wave private strip

    bf16x8 aQ[4];
    const bf16_t* qrow = G3c + (size_t)(qbase + rlo) * 256 + khi * 8;
#pragma unroll
    for (int ks = 0; ks < 4; ++ks) aQ[ks] = *(const bf16x8*)(qrow + ks * 32);

    float m_run[4], l_run[4];
#pragma unroll
    for (int r = 0; r < 4; ++r) { m_run[r] = -1e30f; l_run[r] = 0.f; }
    f32x4 O[16];
#pragma unroll
    for (int i = 0; i < 16; ++i) O[i] = (f32x4){0.f, 0.f, 0.f, 0.f};

    const float scale = 0.088388347648318447f;   // 1/sqrt(128)

    for (int kt = kt0; kt < kt1; ++kt) {
        f32x4 s[4] = {};
#pragma unroll
        for (int ks = 0; ks < 4; ++ks) {
            const bf16_t* kp = Kp + ((size_t)(kt*4 + ks) * 256 + lane) * 8;
#pragma unroll
            for (int nf = 0; nf < 4; ++nf) {
                bf16x8 bK = *(const bf16x8*)(kp + nf * 512);
                s[nf] = MFMA16(aQ[ks], bK, s[nf]);
            }
        }
        int kbase = kt * 64;
#pragma unroll
        for (int nf = 0; nf < 4; ++nf) {
            bool valid = (kbase + nf*16 + rlo) < nS;
#pragma unroll
            for (int r = 0; r < 4; ++r) {
                float v = s[nf][r] * scale;
                s[nf][r] = valid ? v : -1e30f;
            }
        }
        float pm[4];
#pragma unroll
        for (int r = 0; r < 4; ++r)
            pm[r] = fmaxf(fmaxf(s[0][r], s[1][r]), fmaxf(s[2][r], s[3][r]));
#pragma unroll
        for (int off = 1; off < 16; off <<= 1)
#pragma unroll
            for (int r = 0; r < 4; ++r) pm[r] = fmaxf(pm[r], __shfl_xor(pm[r], off, 64));

        float mn[4], sc[4], rs[4];
#pragma unroll
        for (int r = 0; r < 4; ++r) {
            mn[r] = fmaxf(m_run[r], pm[r]);
            sc[r] = __expf(m_run[r] - mn[r]);
            m_run[r] = mn[r];
            rs[r] = 0.f;
        }
#pragma unroll
        for (int nf = 0; nf < 4; ++nf)
#pragma unroll
            for (int r = 0; r < 4; ++r) {
                float p = __expf(s[nf][r] - mn[r]);
                s[nf][r] = p;
                rs[r] += p;
            }
#pragma unroll
        for (int off = 1; off < 16; off <<= 1)
#pragma unroll
            for (int r = 0; r < 4; ++r) rs[r] += __shfl_xor(rs[r], off, 64);
#pragma unroll
        for (int r = 0; r < 4; ++r) l_run[r] = l_run[r]*sc[r] + rs[r];
#pragma unroll
        for (int nf = 0; nf < 16; ++nf)
#pragma unroll
            for (int r = 0; r < 4; ++r) O[nf][r] *= sc[r];
        // P -> per-wave LDS strip, read back in a-frag layout (in-wave dep, no barrier needed)
#pragma unroll
        for (int nf = 0; nf < 4; ++nf)
#pragma unroll
            for (int r = 0; r < 4; ++r)
                P_lds[w][khi*4 + r][nf*16 + rlo] = (bf16_t)s[nf][r];
#pragma unroll
        for (int ks2 = 0; ks2 < 2; ++ks2) {
            bf16x8 pa = *(const bf16x8*)&P_lds[w][rlo][ks2*32 + khi*8];
            const bf16_t* vp = Vp + ((size_t)(kt*2 + ks2) * 1024 + lane) * 8;
#pragma unroll
            for (int nf = 0; nf < 16; ++nf) {
                bf16x8 bV = *(const bf16x8*)(vp + nf * 512);
                O[nf] = MFMA16(pa, bV, O[nf]);
            }
        }
    }
    if (rlo == 0) {
#pragma unroll
        for (int r = 0; r < 4; ++r) {
            int qc = qbase + khi*4 + r;
            pml[((size_t)c*N_CODE + qc)*2 + 0] = m_run[r];
            pml[((size_t)c*N_CODE + qc)*2 + 1] = l_run[r];
        }
    }
#pragma unroll
    for (int nf = 0; nf < 16; ++nf) {
        int d = nf*16 + rlo;
#pragma unroll
        for (int r = 0; r < 4; ++r) {
            int qc = qbase + khi*4 + r;
            pO[((size_t)c*N_CODE + qc)*256 + d] = (bf16_t)O[nf][r];
        }
    }
}

// ---- merge key-split partials, VECTORIZED: thread (qi,j8) owns 8 cols of one q-row ----
template<int KS>
__global__ __launch_bounds__(256)
void tl_merge_t(const bf16_t* __restrict__ pO, const float* __restrict__ pml,
                const int* __restrict__ idxS, const int* __restrict__ counts,
                float* __restrict__ h_new, unsigned* __restrict__ u23)
{
    int nS = counts[0];
    int i0 = blockIdx.x * 8;
    if (i0 >= nS) return;
    int tid = threadIdx.x;
    int qi = tid >> 5;            // 0..7
    int j8 = tid & 31;            // column octet
    int q  = i0 + qi;

    __shared__ unsigned smax[256];
    smax[tid] = 0x007FFFFFu;      // umap(-inf)
    __syncthreads();

    if (q < nS) {
        float m = -1e30f;
#pragma unroll
        for (int cc = 0; cc < KS; ++cc)
            m = fmaxf(m, pml[((size_t)cc*N_CODE + q)*2 + 0]);
        float e[KS]; float l = 0.f;
#pragma unroll
        for (int cc = 0; cc < KS; ++cc) {
            e[cc] = __expf(pml[((size_t)cc*N_CODE + q)*2 + 0] - m);
            l += pml[((size_t)cc*N_CODE + q)*2 + 1] * e[cc];
        }
        float acc[8] = {};
#pragma unroll
        for (int cc = 0; cc < KS; ++cc) {
            bf16x8 v = *(const bf16x8*)(pO + ((size_t)cc*N_CODE + q)*256 + j8*8);
#pragma unroll
            for (int k = 0; k < 8; ++k) acc[k] += (float)v[k] * e[cc];
        }
        float linv = 1.f / fmaxf(l, 1e-30f);
        f32x4 o0, o1;
#pragma unroll
        for (int k = 0; k < 8; ++k) {
            float val = tanhf(acc[k] * linv);
            if (k < 4) o0[k] = val; else o1[k-4] = val;
            atomicMax(&smax[j8*8 + k], umap_f(val));   // LDS atomic (block-local)
        }
        float* dst = h_new + (size_t)idxS[q]*256 + j8*8;
        *(f32x4*)dst = o0;
        *(f32x4*)(dst + 4) = o1;
    }
    __syncthreads();
    atomicMax(&u23[tid], smax[tid]);   // one global atomic per column per block
}

__global__ void tl_final(const unsigned* __restrict__ u1, const unsigned* __restrict__ u23,
                         float* __restrict__ out)
{
    int d = threadIdx.x;
    out[d] = fmaxf(unmap_f(u1[d]), unmap_f(u23[d]));
}

extern "C" void kernel_launch(void* const* d_in, const int* in_sizes, int n_in,
                              void* d_out, int out_size, void* d_ws, size_t ws_size,
                              hipStream_t stream) {
    const float* m_emb  = (const float*)d_in[0];
    const float* ddi    = (const float*)d_in[1];
    const float* unrel  = (const float*)d_in[2];
    const float* hidden = (const float*)d_in[3];
    const float* W_ih   = (const float*)d_in[4];
    const float* W_hh   = (const float*)d_in[5];
    const float* b_ih   = (const float*)d_in[6];
    const float* b_hh   = (const float*)d_in[7];
    const float* Wq     = (const float*)d_in[8];
    const float* bq     = (const float*)d_in[9];
    const float* Wk     = (const float*)d_in[10];
    const float* bk     = (const float*)d_in[11];
    const float* Wv     = (const float*)d_in[12];
    const float* bv     = (const float*)d_in[13];
    const int*   divided= (const int*)d_in[14];

    char* ws = (char*)d_ws;
    bf16_t* B1p   = (bf16_t*)(ws + OFF_B1);
    bf16_t* B2p   = (bf16_t*)(ws + OFF_B2);
    bf16_t* B3p   = (bf16_t*)(ws + OFF_B3);
    bf16_t* BVp   = (bf16_t*)(ws + OFF_BV);
    float*  biases= (float*)(ws + OFF_BIAS);
    unsigned* u1  = (unsigned*)(ws + OFF_U1);
    unsigned* u23 = (unsigned*)(ws + OFF_U23);
    int*    counts= (int*)(ws + OFF_CNT);
    int*    idxS  = (int*)(ws + OFF_IDXS);
    int*    idxM1 = (int*)(ws + OFF_IDXM);
    bf16_t* gxc   = (bf16_t*)(ws + OFF_GXC);
    bf16_t* ghc   = (bf16_t*)(ws + OFF_GHC);
    bf16_t* G3c   = (bf16_t*)(ws + OFF_G3C);
    bf16_t* Vt    = (bf16_t*)(ws + OFF_VT);
    bf16_t* Kp    = (bf16_t*)(ws + OFF_KP);
    bf16_t* Vp    = (bf16_t*)(ws + OFF_VP);
    float*  pml   = (float*)(ws + OFF_PML);
    bf16_t* pO    = (bf16_t*)(ws + OFF_PO);

    // key-split factor from available workspace
    int ksplit;
    if (ws_size >= OFF_PO + (size_t)8 * 4194304)      ksplit = 8;
    else if (ws_size >= OFF_PO + (size_t)4 * 4194304) ksplit = 4;
    else                                              ksplit = 2;

    float* out   = (float*)d_out;
    float* h_new = out + 256;

    tl_prep_scan<<<dim3(129), dim3(1024), 0, stream>>>(W_ih, W_hh, Wq, Wk, Wv, b_ih, b_hh, bq, bk, bv,
                                                       divided, B1p, B2p, B3p, BVp, biases, u1, u23,
                                                       idxS, idxM1, counts);
    tl_gemm_quad<<<dim3(128, 32), dim3(256), 0, stream>>>(m_emb, hidden, ddi, unrel, divided,
                                                          B1p, B2p, B3p, BVp, biases,
                                                          gxc, ghc, G3c, Vt, idxM1, idxS, counts);
    tl_gru_pack<<<dim3(3072), dim3(256), 0, stream>>>(gxc, ghc, hidden, idxM1, counts, h_new, u1,
                                                      G3c, Vt, Kp, Vp);
    tl_attn<<<dim3(ksplit, 128), dim3(256), 0, stream>>>(G3c, Kp, Vp, counts, ksplit, pml, pO);
    if (ksplit == 8)      tl_merge_t<8><<<dim3(1024), dim3(256), 0, stream>>>(pO, pml, idxS, counts, h_new, u23);
    else if (ksplit == 4) tl_merge_t<4><<<dim3(1024), dim3(256), 0, stream>>>(pO, pml, idxS, counts, h_new, u23);
    else                  tl_merge_t<2><<<dim3(1024), dim3(256), 0, stream>>>(pO, pml, idxS, counts, h_new, u23);
    tl_final<<<dim3(1), dim3(256), 0, stream>>>(u1, u23, out);
}

// Round 13
// 147.050 us; speedup vs baseline: 1.7814x; 1.2413x over previous
//
#include <hip/hip_runtime.h>

typedef __bf16 bf16_t;
typedef __bf16 bf16x8 __attribute__((ext_vector_type(8)));
typedef float f32x4 __attribute__((ext_vector_type(4)));

#define MFMA16(A, B, C) __builtin_amdgcn_mfma_f32_16x16x32_bf16(A, B, C, 0, 0, 0)

static constexpr int N_CODE = 8192;

// ---- workspace layout (bytes), de-aliased: gxc/ghc/G3c/Vt simultaneously live ----
static constexpr size_t OFF_B1   = 0;                       // 393216
static constexpr size_t OFF_B2   = OFF_B1 + 393216;         // 393216
static constexpr size_t OFF_B3   = OFF_B2 + 393216;         // 131072
static constexpr size_t OFF_BV   = OFF_B3 + 131072;         // 131072
static constexpr size_t OFF_BIAS = OFF_BV + 131072;         // 8192
static constexpr size_t OFF_U1   = OFF_BIAS + 8192;         // 1024
static constexpr size_t OFF_U23  = OFF_U1 + 1024;           // 1024
static constexpr size_t OFF_CNT  = OFF_U23 + 1024;          // 256
static constexpr size_t OFF_IDXS = OFF_CNT + 256;           // 32768
static constexpr size_t OFF_IDXM = OFF_IDXS + 32768;        // 32768
static constexpr size_t OFF_GXC  = OFF_IDXM + 32768;        // 12582912
static constexpr size_t OFF_GHC  = OFF_GXC + 12582912;      // 12582912
static constexpr size_t OFF_G3C  = OFF_GHC + 12582912;      // 4194304
static constexpr size_t OFF_VT   = OFF_G3C + 4194304;       // 4194304
static constexpr size_t OFF_KP   = OFF_VT + 4194304;        // 2097152
static constexpr size_t OFF_VP   = OFF_KP + 2097152;        // 4194304
static constexpr size_t OFF_PML  = OFF_VP + 4194304;        // 524288
static constexpr size_t OFF_PO   = OFF_PML + 524288;        // ksplit*4194304 (<=33.5MB)
// NOTE (round 9): NO device-scope fences / cross-block done-counters (+60us XCD L2 writeback).
// NOTE (round 11): NO register-staged K/V tiles in attn (spills -> 120MB scratch writes).
// NOTE (round 12): gemm VGPR=36 = serialized load->MFMA chain; fix = 4 n-frags/wave (this round).

__device__ __forceinline__ unsigned umap_f(float f) {
    unsigned u = __float_as_uint(f);
    return (u & 0x80000000u) ? ~u : (u | 0x80000000u);   // monotone: larger float -> larger uint
}
__device__ __forceinline__ float unmap_f(unsigned u) {
    unsigned b = (u & 0x80000000u) ? (u & 0x7fffffffu) : ~u;
    return __uint_as_float(b);
}

// ---- fused: block 0 = compaction scan (shfl-based); blocks 1..128 = weight pack ----
__global__ __launch_bounds__(1024)
void tl_prep_scan(const float* __restrict__ W_ih, const float* __restrict__ W_hh,
                  const float* __restrict__ Wq, const float* __restrict__ Wk,
                  const float* __restrict__ Wv,
                  const float* __restrict__ b_ih, const float* __restrict__ b_hh,
                  const float* __restrict__ bq, const float* __restrict__ bk,
                  const float* __restrict__ bv,
                  const int* __restrict__ divided,
                  bf16_t* __restrict__ B1p, bf16_t* __restrict__ B2p,
                  bf16_t* __restrict__ B3p, bf16_t* __restrict__ BVp,
                  float* __restrict__ biases,
                  unsigned* __restrict__ u1, unsigned* __restrict__ u23,
                  int* __restrict__ idxS, int* __restrict__ idxM1, int* __restrict__ counts)
{
    int t = threadIdx.x;
    if (blockIdx.x == 0) {
        __shared__ int w1[16], w23[16];
        int lane = t & 63, wv = t >> 6;
        int d[8]; int c1 = 0, c23 = 0;
#pragma unroll
        for (int i = 0; i < 8; ++i) {
            d[i] = divided[t*8 + i];
            c1  += (d[i] == 0);
            c23 += (d[i] != 0);
        }
        int s1v = c1, s23v = c23;
#pragma unroll
        for (int off = 1; off < 64; off <<= 1) {
            int a1  = __shfl_up(s1v,  off, 64);
            int a23 = __shfl_up(s23v, off, 64);
            if (lane >= off) { s1v += a1; s23v += a23; }
        }
        if (lane == 63) { w1[wv] = s1v; w23[wv] = s23v; }
        __syncthreads();
        if (wv == 0 && lane < 16) {
            int v1 = w1[lane], v23 = w23[lane];
#pragma unroll
            for (int off = 1; off < 16; off <<= 1) {
                int a1  = __shfl_up(v1,  off, 16);
                int a23 = __shfl_up(v23, off, 16);
                if (lane >= off) { v1 += a1; v23 += a23; }
            }
            w1[lane] = v1; w23[lane] = v23;
        }
        __syncthreads();
        int base1  = (wv > 0) ? w1[wv-1]  : 0;
        int base23 = (wv > 0) ? w23[wv-1] : 0;
        int o1  = base1  + s1v  - c1;
        int o23 = base23 + s23v - c23;
#pragma unroll
        for (int i = 0; i < 8; ++i) {
            if (d[i] == 0) idxM1[o1++] = t*8 + i;
            else           idxS[o23++] = t*8 + i;
        }
        if (t == 1023) { counts[0] = w23[15]; counts[1] = w1[15]; }
        return;
    }
    int idx = (blockIdx.x - 1) * 1024 + t;
    const int T1 = 196608, T2 = 196608, T3 = 65536, T4 = 65536;
    for (int i = idx; i < T1 + T2 + T3 + T4; i += 128 * 1024) {
        int which, l;
        if (i < T1)                { which = 0; l = i; }
        else if (i < T1 + T2)      { which = 1; l = i - T1; }
        else if (i < T1 + T2 + T3) { which = 2; l = i - T1 - T2; }
        else                       { which = 3; l = i - T1 - T2 - T3; }
        int j = l & 7, lane = (l >> 3) & 63, kk = (l >> 9) & 7, n16 = l >> 12;
        int k = kk*32 + (lane >> 4)*8 + j;      // K index 0..255
        int n = n16*16 + (lane & 15);           // output column
        if (which == 0)      B1p[l] = (bf16_t)W_ih[n*256 + k];
        else if (which == 1) B2p[l] = (bf16_t)W_hh[n*256 + k];
        else if (which == 2) B3p[l] = (bf16_t)((n < 128) ? Wq[k*128 + n] : Wk[k*128 + (n - 128)]);
        else                 BVp[l] = (bf16_t)Wv[k*256 + n];
    }
    if (idx < 768)       biases[idx] = b_ih[idx];
    else if (idx < 1536) biases[idx] = b_hh[idx - 768];
    else if (idx < 1792) { int q = idx - 1536; biases[idx] = (q < 128) ? bq[q] : bk[q - 128]; }
    else if (idx < 2048) biases[idx] = bv[idx - 1792];
    if (idx < 256) { u1[idx] = 0x007FFFFFu; u23[idx] = 0x007FFFFFu; }  // umap(-inf)
}

__device__ __forceinline__ bf16x8 load_cvt8(const float* p) {
    f32x4 a = *(const f32x4*)p;
    f32x4 b = *(const f32x4*)(p + 4);
    bf16x8 r;
#pragma unroll
    for (int j = 0; j < 4; ++j) { r[j] = (bf16_t)a[j]; r[j+4] = (bf16_t)b[j]; }
    return r;
}

// ---- quad gathered GEMM, WIDE: each wave owns 64 cols (4 n-frags); each A-frag feeds 4 MFMAs ----
// y<3: gxc = m_emb[idxM1]@B1p | y<6: ghc = hidden[idxM1]@B2p
// y==6: G3c = sel(ddi,unrel)[idxS]@B3p | y==7: Vt = m_emb[idxS]@BVp
__global__ __launch_bounds__(256, 2)
void tl_gemm_quad(const float* __restrict__ m_emb, const float* __restrict__ hidden,
                  const float* __restrict__ ddi, const float* __restrict__ unrel,
                  const int* __restrict__ divided,
                  const bf16_t* __restrict__ B1p, const bf16_t* __restrict__ B2p,
                  const bf16_t* __restrict__ B3p, const bf16_t* __restrict__ BVp,
                  const float* __restrict__ biases,
                  bf16_t* __restrict__ gxc, bf16_t* __restrict__ ghc,
                  bf16_t* __restrict__ G3c, bf16_t* __restrict__ Vt,
                  const int* __restrict__ idxM1, const int* __restrict__ idxS,
                  const int* __restrict__ counts)
{
    int y = blockIdx.y;
    const float* A0; const float* A1 = nullptr; int mode = 0;
    const bf16_t* Bp; const float* bias; bf16_t* C; int NOUT; int y0;
    const int* gidx; int cnt;
    if (y < 3)       { A0 = m_emb;  gidx = idxM1; cnt = counts[1]; Bp = B1p; bias = biases;        C = gxc; NOUT = 768; y0 = y; }
    else if (y < 6)  { A0 = hidden; gidx = idxM1; cnt = counts[1]; Bp = B2p; bias = biases + 768;  C = ghc; NOUT = 768; y0 = y - 3; }
    else if (y == 6) { A0 = ddi; A1 = unrel; mode = 2;
                       gidx = idxS;  cnt = counts[0]; Bp = B3p; bias = biases + 1536; C = G3c; NOUT = 256; y0 = 0; }
    else             { A0 = m_emb;  gidx = idxS;  cnt = counts[0]; Bp = BVp; bias = biases + 1792; C = Vt;  NOUT = 256; y0 = 0; }

    int m0 = blockIdx.x * 64;
    if (m0 >= cnt) return;
    int lane = threadIdx.x & 63;
    int w    = threadIdx.x >> 6;
    int rlo = lane & 15, khi = lane >> 4;
    int nbase = y0 * 256 + w * 64;   // wave's 64-column strip

    const float* arow[4];
#pragma unroll
    for (int m = 0; m < 4; ++m) {
        int row = m0 + m*16 + rlo;
        int src = gidx[(row < cnt) ? row : 0];
        const float* base = A0;
        if (mode == 2) base = (divided[src] == 1) ? A0 : A1;
        arow[m] = base + (size_t)src * 256;
    }
    f32x4 acc[4][4] = {};   // [m][nf], static indices only
    const bf16_t* bptr = Bp + (size_t)(nbase >> 4) * 4096 + lane * 8;
#pragma unroll
    for (int kk = 0; kk < 8; ++kk) {
        bf16x8 bfrag[4];
#pragma unroll
        for (int nf = 0; nf < 4; ++nf)
            bfrag[nf] = *(const bf16x8*)(bptr + nf * 4096 + kk * 512);
#pragma unroll
        for (int m = 0; m < 4; ++m) {
            bf16x8 afrag = load_cvt8(arow[m] + kk*32 + khi*8);
#pragma unroll
            for (int nf = 0; nf < 4; ++nf)
                acc[m][nf] = MFMA16(afrag, bfrag[nf], acc[m][nf]);
        }
    }
#pragma unroll
    for (int nf = 0; nf < 4; ++nf) {
        int col = nbase + nf*16 + rlo;
        float b = bias[col];
#pragma unroll
        for (int m = 0; m < 4; ++m)
#pragma unroll
            for (int r = 0; r < 4; ++r) {
                int row = m0 + m*16 + khi*4 + r;   // compact row index
                C[(size_t)row * NOUT + col] = (bf16_t)(acc[m][nf][r] + b);
            }
    }
}

// ---- fused gru (blocks 0..1023) + pack (blocks 1024..3071); disjoint data ----
__global__ __launch_bounds__(256)
void tl_gru_pack(const bf16_t* __restrict__ gx, const bf16_t* __restrict__ gh,
                 const float* __restrict__ hidden,
                 const int* __restrict__ idxM1, const int* __restrict__ counts,
                 float* __restrict__ h_new, unsigned* __restrict__ u1,
                 const bf16_t* __restrict__ G3c, const bf16_t* __restrict__ Vt,
                 bf16_t* __restrict__ Kp, bf16_t* __restrict__ Vp)
{
    if (blockIdx.x < 1024) {
        int nM1 = counts[1];
        int i0 = blockIdx.x * 8;
        if (i0 >= nM1) return;
        int j = threadIdx.x;
        int iend = (i0 + 8 < nM1) ? i0 + 8 : nM1;
        float cmax = -1e30f;
        for (int i = i0; i < iend; ++i) {
            int row = idxM1[i];
            float xr = (float)gx[(size_t)i*768 + j];
            float xz = (float)gx[(size_t)i*768 + 256 + j];
            float xn = (float)gx[(size_t)i*768 + 512 + j];
            float hr = (float)gh[(size_t)i*768 + j];
            float hz = (float)gh[(size_t)i*768 + 256 + j];
            float hn = (float)gh[(size_t)i*768 + 512 + j];
            float h  = hidden[(size_t)row*256 + j];
            float r = 1.f/(1.f + __expf(-(xr + hr)));
            float z = 1.f/(1.f + __expf(-(xz + hz)));
            float n = tanhf(xn + r*hn);
            float hg = (1.f - z)*n + z*h;
            h_new[(size_t)row*256 + j] = hg;
            cmax = fmaxf(cmax, hg);
        }
        atomicMax(&u1[j], umap_f(cmax));
        return;
    }
    int nS = counts[0];
    int nT = (nS + 63) >> 6;
    int r = (blockIdx.x - 1024) * 4 + (threadIdx.x >> 6);
    if (r >= nT * 64) return;
    int t = threadIdx.x & 63;
    bool valid = r < nS;
    if (t < 16) {                 // K b-frags: [kt][ks4][nf4][lane][8]
        bf16x8 v = {};
        if (valid) v = *(const bf16x8*)(G3c + (size_t)r*256 + 128 + t*8);
        int kt = r >> 6, keyin = r & 63;
        int ks = t >> 2, lhi = t & 3, nf = keyin >> 4;
        int lane = (lhi << 4) | (keyin & 15);
        *(bf16x8*)(Kp + ((((size_t)kt*4 + ks)*4 + nf)*64 + lane)*8) = v;
    } else if (t < 48) {          // V b-frags: [kt][ks2][nf16][lane][8]
        int j8 = t - 16;
        int d0 = j8 * 8;
        bf16x8 v = {};
        if (valid) v = *(const bf16x8*)(Vt + (size_t)r*256 + d0);
        int kt = r >> 6, ks2 = (r >> 5) & 1, jj = r & 7, lhi = (r >> 3) & 3;
#pragma unroll
        for (int q = 0; q < 8; ++q) {
            int d = d0 + q;
            int nf = d >> 4;
            int lane = (lhi << 4) | (d & 15);
            Vp[((((size_t)kt*2 + ks2)*16 + nf)*64 + lane)*8 + jj] = v[q];
        }
    }
}

// ---- flash attention (BYTE-STABLE round-5 body); grid (ksplit, 128) XCD-locality swap ----
__global__ __launch_bounds__(256, 2)
void tl_attn(const bf16_t* __restrict__ G3c, const bf16_t* __restrict__ Kp,
             const bf16_t* __restrict__ Vp, const int* __restrict__ counts,
             int ksplit, float* __restrict__ pml, bf16_t* __restrict__ pO)
{
    int nS = counts[0];
    int nT = (nS + 63) >> 6;
    int qt = blockIdx.y;
    if (qt >= nT) return;
    int c = blockIdx.x;
    int kt0 = (nT * c) / ksplit, kt1 = (nT * (c + 1)) / ksplit;

    int lane = threadIdx.x & 63;
    int w    = threadIdx.x >> 6;
    int rlo = lane & 15, khi = lane >> 4;
    int qbase = qt * 64 + w * 16;

    __shared__ __align__(16) bf16_t P_lds[4][16][72];   // per-wave private strip

    bf16x8 aQ[4];
    const bf16_t* qrow = G3c + (size_t)(qbase + rlo) * 256 + khi * 8;
#pragma unroll
    for (int ks = 0; ks < 4; ++ks) aQ[ks] = *(const bf16x8*)(qrow + ks * 32);

    float m_run[4], l_run[4];
#pragma unroll
    for (int r = 0; r < 4; ++r) { m_run[r] = -1e30f; l_run[r] = 0.f; }
    f32x4 O[16];
#pragma unroll
    for (int i = 0; i < 16; ++i) O[i] = (f32x4){0.f, 0.f, 0.f, 0.f};

    const float scale = 0.088388347648318447f;   // 1/sqrt(128)

    for (int kt = kt0; kt < kt1; ++kt) {
        f32x4 s[4] = {};
#pragma unroll
        for (int ks = 0; ks < 4; ++ks) {
            const bf16_t* kp = Kp + ((size_t)(kt*4 + ks) * 256 + lane) * 8;
#pragma unroll
            for (int nf = 0; nf < 4; ++nf) {
                bf16x8 bK = *(const bf16x8*)(kp + nf * 512);
                s[nf] = MFMA16(aQ[ks], bK, s[nf]);
            }
        }
        int kbase = kt * 64;
#pragma unroll
        for (int nf = 0; nf < 4; ++nf) {
            bool valid = (kbase + nf*16 + rlo) < nS;
#pragma unroll
            for (int r = 0; r < 4; ++r) {
                float v = s[nf][r] * scale;
                s[nf][r] = valid ? v : -1e30f;
            }
        }
        float pm[4];
#pragma unroll
        for (int r = 0; r < 4; ++r)
            pm[r] = fmaxf(fmaxf(s[0][r], s[1][r]), fmaxf(s[2][r], s[3][r]));
#pragma unroll
        for (int off = 1; off < 16; off <<= 1)
#pragma unroll
            for (int r = 0; r < 4; ++r) pm[r] = fmaxf(pm[r], __shfl_xor(pm[r], off, 64));

        float mn[4], sc[4], rs[4];
#pragma unroll
        for (int r = 0; r < 4; ++r) {
            mn[r] = fmaxf(m_run[r], pm[r]);
            sc[r] = __expf(m_run[r] - mn[r]);
            m_run[r] = mn[r];
            rs[r] = 0.f;
        }
#pragma unroll
        for (int nf = 0; nf < 4; ++nf)
#pragma unroll
            for (int r = 0; r < 4; ++r) {
                float p = __expf(s[nf][r] - mn[r]);
                s[nf][r] = p;
                rs[r] += p;
            }
#pragma unroll
        for (int off = 1; off < 16; off <<= 1)
#pragma unroll
            for (int r = 0; r < 4; ++r) rs[r] += __shfl_xor(rs[r], off, 64);
#pragma unroll
        for (int r = 0; r < 4; ++r) l_run[r] = l_run[r]*sc[r] + rs[r];
#pragma unroll
        for (int nf = 0; nf < 16; ++nf)
#pragma unroll
            for (int r = 0; r < 4; ++r) O[nf][r] *= sc[r];
        // P -> per-wave LDS strip, read back in a-frag layout (in-wave dep, no barrier needed)
#pragma unroll
        for (int nf = 0; nf < 4; ++nf)
#pragma unroll
            for (int r = 0; r < 4; ++r)
                P_lds[w][khi*4 + r][nf*16 + rlo] = (bf16_t)s[nf][r];
#pragma unroll
        for (int ks2 = 0; ks2 < 2; ++ks2) {
            bf16x8 pa = *(const bf16x8*)&P_lds[w][rlo][ks2*32 + khi*8];
            const bf16_t* vp = Vp + ((size_t)(kt*2 + ks2) * 1024 + lane) * 8;
#pragma unroll
            for (int nf = 0; nf < 16; ++nf) {
                bf16x8 bV = *(const bf16x8*)(vp + nf * 512);
                O[nf] = MFMA16(pa, bV, O[nf]);
            }
        }
    }
    if (rlo == 0) {
#pragma unroll
        for (int r = 0; r < 4; ++r) {
            int qc = qbase + khi*4 + r;
            pml[((size_t)c*N_CODE + qc)*2 + 0] = m_run[r];
            pml[((size_t)c*N_CODE + qc)*2 + 1] = l_run[r];
        }
    }
#pragma unroll
    for (int nf = 0; nf < 16; ++nf) {
        int d = nf*16 + rlo;
#pragma unroll
        for (int r = 0; r < 4; ++r) {
            int qc = qbase + khi*4 + r;
            pO[((size_t)c*N_CODE + qc)*256 + d] = (bf16_t)O[nf][r];
        }
    }
}

// ---- merge key-split partials, VECTORIZED: thread (qi,j8) owns 8 cols of one q-row ----
template<int KS>
__global__ __launch_bounds__(256)
void tl_merge_t(const bf16_t* __restrict__ pO, const float* __restrict__ pml,
                const int* __restrict__ idxS, const int* __restrict__ counts,
                float* __restrict__ h_new, unsigned* __restrict__ u23)
{
    int nS = counts[0];
    int i0 = blockIdx.x * 8;
    if (i0 >= nS) return;
    int tid = threadIdx.x;
    int qi = tid >> 5;
    int j8 = tid & 31;
    int q  = i0 + qi;

    __shared__ unsigned smax[256];
    smax[tid] = 0x007FFFFFu;      // umap(-inf)
    __syncthreads();

    if (q < nS) {
        float m = -1e30f;
#pragma unroll
        for (int cc = 0; cc < KS; ++cc)
            m = fmaxf(m, pml[((size_t)cc*N_CODE + q)*2 + 0]);
        float e[KS]; float l = 0.f;
#pragma unroll
        for (int cc = 0; cc < KS; ++cc) {
            e[cc] = __expf(pml[((size_t)cc*N_CODE + q)*2 + 0] - m);
            l += pml[((size_t)cc*N_CODE + q)*2 + 1] * e[cc];
        }
        float acc[8] = {};
#pragma unroll
        for (int cc = 0; cc < KS; ++cc) {
            bf16x8 v = *(const bf16x8*)(pO + ((size_t)cc*N_CODE + q)*256 + j8*8);
#pragma unroll
            for (int k = 0; k < 8; ++k) acc[k] += (float)v[k] * e[cc];
        }
        float linv = 1.f / fmaxf(l, 1e-30f);
        f32x4 o0, o1;
#pragma unroll
        for (int k = 0; k < 8; ++k) {
            float val = tanhf(acc[k] * linv);
            if (k < 4) o0[k] = val; else o1[k-4] = val;
            atomicMax(&smax[j8*8 + k], umap_f(val));   // LDS atomic (block-local)
        }
        float* dst = h_new + (size_t)idxS[q]*256 + j8*8;
        *(f32x4*)dst = o0;
        *(f32x4*)(dst + 4) = o1;
    }
    __syncthreads();
    atomicMax(&u23[tid], smax[tid]);   // one global atomic per column per block
}

__global__ void tl_final(const unsigned* __restrict__ u1, const unsigned* __restrict__ u23,
                         float* __restrict__ out)
{
    int d = threadIdx.x;
    out[d] = fmaxf(unmap_f(u1[d]), unmap_f(u23[d]));
}

extern "C" void kernel_launch(void* const* d_in, const int* in_sizes, int n_in,
                              void* d_out, int out_size, void* d_ws, size_t ws_size,
                              hipStream_t stream) {
    const float* m_emb  = (const float*)d_in[0];
    const float* ddi    = (const float*)d_in[1];
    const float* unrel  = (const float*)d_in[2];
    const float* hidden = (const float*)d_in[3];
    const float* W_ih   = (const float*)d_in[4];
    const float* W_hh   = (const float*)d_in[5];
    const float* b_ih   = (const float*)d_in[6];
    const float* b_hh   = (const float*)d_in[7];
    const float* Wq     = (const float*)d_in[8];
    const float* bq     = (const float*)d_in[9];
    const float* Wk     = (const float*)d_in[10];
    const float* bk     = (const float*)d_in[11];
    const float* Wv     = (const float*)d_in[12];
    const float* bv     = (const float*)d_in[13];
    const int*   divided= (const int*)d_in[14];

    char* ws = (char*)d_ws;
    bf16_t* B1p   = (bf16_t*)(ws + OFF_B1);
    bf16_t* B2p   = (bf16_t*)(ws + OFF_B2);
    bf16_t* B3p   = (bf16_t*)(ws + OFF_B3);
    bf16_t* BVp   = (bf16_t*)(ws + OFF_BV);
    float*  biases= (float*)(ws + OFF_BIAS);
    unsigned* u1  = (unsigned*)(ws + OFF_U1);
    unsigned* u23 = (unsigned*)(ws + OFF_U23);
    int*    counts= (int*)(ws + OFF_CNT);
    int*    idxS  = (int*)(ws + OFF_IDXS);
    int*    idxM1 = (int*)(ws + OFF_IDXM);
    bf16_t* gxc   = (bf16_t*)(ws + OFF_GXC);
    bf16_t* ghc   = (bf16_t*)(ws + OFF_GHC);
    bf16_t* G3c   = (bf16_t*)(ws + OFF_G3C);
    bf16_t* Vt    = (bf16_t*)(ws + OFF_VT);
    bf16_t* Kp    = (bf16_t*)(ws + OFF_KP);
    bf16_t* Vp    = (bf16_t*)(ws + OFF_VP);
    float*  pml   = (float*)(ws + OFF_PML);
    bf16_t* pO    = (bf16_t*)(ws + OFF_PO);

    int ksplit;
    if (ws_size >= OFF_PO + (size_t)8 * 4194304)      ksplit = 8;
    else if (ws_size >= OFF_PO + (size_t)4 * 4194304) ksplit = 4;
    else                                              ksplit = 2;

    float* out   = (float*)d_out;
    float* h_new = out + 256;

    tl_prep_scan<<<dim3(129), dim3(1024), 0, stream>>>(W_ih, W_hh, Wq, Wk, Wv, b_ih, b_hh, bq, bk, bv,
                                                       divided, B1p, B2p, B3p, BVp, biases, u1, u23,
                                                       idxS, idxM1, counts);
    tl_gemm_quad<<<dim3(128, 8), dim3(256), 0, stream>>>(m_emb, hidden, ddi, unrel, divided,
                                                         B1p, B2p, B3p, BVp, biases,
                                                         gxc, ghc, G3c, Vt, idxM1, idxS, counts);
    tl_gru_pack<<<dim3(3072), dim3(256), 0, stream>>>(gxc, ghc, hidden, idxM1, counts, h_new, u1,
                                                      G3c, Vt, Kp, Vp);
    tl_attn<<<dim3(ksplit, 128), dim3(256), 0, stream>>>(G3c, Kp, Vp, counts, ksplit, pml, pO);
    if (ksplit == 8)      tl_merge_t<8><<<dim3(1024), dim3(256), 0, stream>>>(pO, pml, idxS, counts, h_new, u23);
    else if (ksplit == 4) tl_merge_t<4><<<dim3(1024), dim3(256), 0, stream>>>(pO, pml, idxS, counts, h_new, u23);
    else                  tl_merge_t<2><<<dim3(1024), dim3(256), 0, stream>>>(pO, pml, idxS, counts, h_new, u23);
    tl_final<<<dim3(1), dim3(256), 0, stream>>>(u1, u23, out);
}